// Round 9
// baseline (423.092 us; speedup 1.0000x reference)
//
#include <hip/hip_runtime.h>
#include <stdint.h>

#define EFFECT_DIM 758
#define ADD_DIM 10
#define EMBED_DIM 768
#define NCOLS 95000
#define NSYN 8
#define NROWS 1024
#define NT256 372            // ceil(95000/256)
#define TILE_B 32768         // bytes per 256x64 bf16 tile (fragment-ordered)

typedef __attribute__((ext_vector_type(8))) __bf16 bf16x8;
typedef __attribute__((ext_vector_type(16))) float f32x16;
typedef __attribute__((ext_vector_type(4))) uint32_t u32x4;

// Fragment-coalesced tile layout (A and B identical):
//   tile(idx, ks) at (idx*12+ks)*32768
//   byte offset = kk*8192 + grp*1024 + lane*16   (+ byte-in-16)
//   kk = 32-k block (0..3), grp = 32-row group (0..7),
//   lane = (row&31) + (khalf16B << 5)  -> exactly MFMA fragment order:
//   a frag for (grp, kk) is a coalesced 1KB load at lane l = threadIdx&63.

// single-instruction f32 pair -> packed bf16 (RNE)
static __device__ __forceinline__ uint32_t pack2(float a, float b) {
  uint32_t r;
  asm("v_cvt_pk_bf16_f32 %0, %1, %2" : "=v"(r) : "v"(a), "v"(b));
  return r;
}

#define F4C(f, i) ((i) == 0 ? (f).x : (i) == 1 ? (f).y : (i) == 2 ? (f).z : (f).w)

// ---------------------------------------------------------------------------
// Kernel 1: VirtualEmbedding -> bf16 A tiles (4 m-tiles x 12 ks), frag order.
// ---------------------------------------------------------------------------
__global__ __launch_bounds__(256) void emb_kernel(
    const int* __restrict__ ids, const float* __restrict__ W_emb,
    const float* __restrict__ padding, const int* __restrict__ syn_table,
    const int* __restrict__ syn_mask, char* __restrict__ ws)
{
  const int l = blockIdx.x;
  const int t = threadIdx.x;
  const int id = ids[l];
  int sid[NSYN];
  int msk[NSYN];
#pragma unroll
  for (int k = 0; k < NSYN; ++k) {
    sid[k] = syn_table[id * NSYN + k];
    msk[k] = syn_mask[id * NSYN + k];
  }

  double p[9] = {0, 0, 0, 0, 0, 0, 0, 0, 0};
  for (int d = t; d < EFFECT_DIM; d += 256) {
    p[0] += (double)W_emb[(size_t)id * EFFECT_DIM + d];
#pragma unroll
    for (int k = 0; k < NSYN; ++k)
      p[k + 1] += (double)W_emb[(size_t)sid[k] * EFFECT_DIM + d];
  }

  __shared__ double s_red[9][4];
  const int w = t >> 6;
#pragma unroll
  for (int k = 0; k < 9; ++k) {
    double v = p[k];
#pragma unroll
    for (int off = 32; off > 0; off >>= 1) v += __shfl_down(v, off, 64);
    if ((t & 63) == 0) s_red[k][w] = v;
  }
  __syncthreads();

  const double isum = s_red[0][0] + s_red[0][1] + s_red[0][2] + s_red[0][3];
  float coef[NSYN];
#pragma unroll
  for (int k = 0; k < NSYN; ++k) {
    double ss = s_red[k + 1][0] + s_red[k + 1][1] + s_red[k + 1][2] + s_red[k + 1][3];
    coef[k] = msk[k] ? (float)(isum / ss) : 0.0f;
  }

  const int r = l & 255;               // row within 256-row tile
  char* wbase = ws + (size_t)(l >> 8) * (12 * TILE_B);

  for (int j = t; j < 384; j += 256) { // bf16-pair index over 768 cols
    const int d0 = 2 * j;
    float v0, v1;
    if (d0 < EFFECT_DIM) {
      const float* bp = W_emb + (size_t)id * EFFECT_DIM + d0;
      v0 = bp[0];
      v1 = bp[1];
#pragma unroll
      for (int k = 0; k < NSYN; ++k) {
        const float* sp = W_emb + (size_t)sid[k] * EFFECT_DIM + d0;
        v0 = fmaf(coef[k], sp[0], v0);
        v1 = fmaf(coef[k], sp[1], v1);
      }
    } else {
      v0 = padding[l * ADD_DIM + (d0 - EFFECT_DIM)];
      v1 = padding[l * ADD_DIM + (d0 + 1 - EFFECT_DIM)];
    }
    const int ks   = j >> 5;           // 64-k tile
    const int jl   = j & 31;           // k-pair within tile
    const int kk   = jl >> 3;          // 32-k block
    const int byte = (jl & 7) * 4;     // 0..28 within 32-k block row
    const int lane = (r & 31) + ((byte >> 4) << 5);
    *(uint32_t*)(wbase + ks * TILE_B + kk * 8192 + (r >> 5) * 1024 +
                 lane * 16 + (byte & 15)) = pack2(v0, v1);
  }
}

// ---------------------------------------------------------------------------
// Kernel 1b: W_rev f32 -> bf16 B tiles (372 n-tiles x 12 ks), frag order.
// Block (j, ks): n in [j*128, j*128+128) = grps (j&1)*4..+3 of tile j>>1.
// float4 loads; LDS bounce for coalesced 16B stores.
// ---------------------------------------------------------------------------
__global__ __launch_bounds__(256) void conv_kernel(
    const float* __restrict__ Wrev, char* __restrict__ Bbuf)
{
  __shared__ char lds[16384];  // [kk 4][grp_half 4][lane 64][16B]
  const int t   = threadIdx.x;
  const int j   = blockIdx.x;          // 0..743
  const int ks  = blockIdx.y;
  const int nl4 = t & 31;              // n-quad
  const int kc  = t >> 5;              // 0..7: 8-k group (16B)
  const int gn4 = j * 128 + nl4 * 4;
  const bool valid = (gn4 + 4) <= NCOLS;

  float4 v[8];
  const float* p = Wrev + (size_t)(ks * 64 + kc * 8) * NCOLS + gn4;
#pragma unroll
  for (int jj = 0; jj < 8; ++jj)
    v[jj] = valid ? *(const float4*)(p + (size_t)jj * NCOLS)
                  : float4{0.0f, 0.0f, 0.0f, 0.0f};

  const int kk  = kc >> 1;
  const int lh2 = kc & 1;
#pragma unroll
  for (int i = 0; i < 4; ++i) {
    const int nloc = nl4 * 4 + i;      // 0..127
    u32x4 u;
#pragma unroll
    for (int j2 = 0; j2 < 4; ++j2)
      u[j2] = pack2(F4C(v[2 * j2], i), F4C(v[2 * j2 + 1], i));
    const int lane = (nloc & 31) + (lh2 << 5);
    *(u32x4*)(lds + kk * 4096 + (nl4 >> 3) * 1024 + lane * 16) = u;
  }
  __syncthreads();

  char* base = Bbuf + (size_t)((j >> 1) * 12 + ks) * TILE_B + (j & 1) * 4096;
#pragma unroll
  for (int i = 0; i < 4; ++i) {
    const int idx = i * 4096 + t * 16;
    const int k2  = idx >> 12;
    const int rem = idx & 4095;
    *(u32x4*)(base + k2 * 8192 + rem) = *(const u32x4*)(lds + idx);
  }
}

// ---------------------------------------------------------------------------
// Kernel 2: LDS-FREE register-streaming GEMM. 256x256 block tile, 512
// threads, 8 waves (2m x 4n), wave-tile 128x64. Per K-tile each wave loads
// its fragments directly global->VGPR (coalesced 1KB dwordx4), 32 MFMA.
// No barriers, no LDS, no manual waitcnt — 8 free-running waves/CU hide
// latency; A is L1/L2-hot (1.5MB), B streams HBM once (T1 XCD remap).
// ---------------------------------------------------------------------------
__global__ __launch_bounds__(512, 2) void gemm_reg(
    const char* __restrict__ Abuf, const char* __restrict__ Bbuf,
    float* __restrict__ out)
{
  const int t  = threadIdx.x;
  const int l  = t & 63;
  const int w  = t >> 6;   // 0..7
  const int wm = w >> 2;   // 0..1
  const int wn = w & 3;    // 0..3
  const int lr = l & 31;
  const int lh = l >> 5;

  const int wgid = blockIdx.x;            // 0..1487 = 8 XCDs x 186
  const int xcd  = wgid & 7;
  const int work = xcd * 186 + (wgid >> 3);
  const int mt = work & 3;
  const int nt = work >> 2;
  const int n0 = nt * 256;

  f32x16 acc[4][2] = {};

  const char* abase = Abuf + (size_t)mt * (12 * TILE_B) + (wm * 4) * 1024 + l * 16;
  const char* bbase = Bbuf + (size_t)nt * (12 * TILE_B) + (wn * 2) * 1024 + l * 16;

  for (int T = 0; T < 12; ++T) {
    const char* at = abase + T * TILE_B;
    const char* bt = bbase + T * TILE_B;
    bf16x8 b[4][2], a[4][4];
#pragma unroll
    for (int kk = 0; kk < 4; ++kk)
#pragma unroll
      for (int nr = 0; nr < 2; ++nr)
        b[kk][nr] = *(const bf16x8*)(bt + kk * 8192 + nr * 1024);
#pragma unroll
    for (int kk = 0; kk < 4; ++kk)
#pragma unroll
      for (int mr = 0; mr < 4; ++mr)
        a[kk][mr] = *(const bf16x8*)(at + kk * 8192 + mr * 1024);
#pragma unroll
    for (int kk = 0; kk < 4; ++kk) {
      __builtin_amdgcn_s_setprio(1);
#pragma unroll
      for (int mr = 0; mr < 4; ++mr)
#pragma unroll
        for (int nr = 0; nr < 2; ++nr)
          acc[mr][nr] = __builtin_amdgcn_mfma_f32_32x32x16_bf16(
              a[kk][mr], b[kk][nr], acc[mr][nr], 0, 0, 0);
      __builtin_amdgcn_s_setprio(0);
    }
  }

  // epilogue: C layout col=lane&31, row=(reg&3)+8*(reg>>2)+4*(lane>>5)
#pragma unroll
  for (int nr = 0; nr < 2; ++nr) {
    const int gc = n0 + wn * 64 + nr * 32 + lr;
    if (gc < NCOLS) {
#pragma unroll
      for (int mr = 0; mr < 4; ++mr)
#pragma unroll
        for (int reg = 0; reg < 16; ++reg) {
          const int row = (reg & 3) + 8 * (reg >> 2) + 4 * lh;
          const int gr = mt * 256 + wm * 128 + mr * 32 + row;
          out[(size_t)gr * NCOLS + gc] = acc[mr][nr][reg];
        }
    }
  }
}

// ---------------------------------------------------------------------------
// Fallback GEMM (ws too small for Bbuf): 128^2 tile, A frags direct from
// global (new layout), B inline-converted into swizzled LDS.
// ---------------------------------------------------------------------------
__global__ __launch_bounds__(256, 2) void gemm_fb(
    const float* __restrict__ Wrev, const char* __restrict__ Abuf,
    float* __restrict__ out)
{
  __shared__ char lds[16384];  // B [128 n][128B k], swz ((n&7)<<4)
  const int t  = threadIdx.x;
  const int l  = t & 63;
  const int w  = t >> 6;
  const int wm = w >> 1;
  const int wn = w & 1;
  const int lr = l & 31;
  const int lh = l >> 5;
  const int mt = blockIdx.x;           // 0..7 (128-row tiles)
  const int n0 = blockIdx.y * 128;

  f32x16 acc[2][2] = {};

  const char* abase = Abuf + (size_t)(mt >> 1) * (12 * TILE_B);
  const int nl = t & 127;
  const int kc_base = t >> 7;
  const int gn = n0 + nl;
  const int bswz = (nl & 7) << 4;

  for (int ks = 0; ks < 12; ++ks) {
#pragma unroll
    for (int task = 0; task < 4; ++task) {
      const int kc = kc_base + task * 2;
      float v[8];
      const float* p = Wrev + (size_t)(ks * 64 + kc * 8) * NCOLS + gn;
#pragma unroll
      for (int j = 0; j < 8; ++j)
        v[j] = (gn < NCOLS) ? p[(size_t)j * NCOLS] : 0.0f;
      u32x4 u;
#pragma unroll
      for (int j = 0; j < 4; ++j)
        u[j] = pack2(v[2 * j], v[2 * j + 1]);
      *(u32x4*)(lds + nl * 128 + ((kc * 16) ^ bswz)) = u;
    }
    __syncthreads();

#pragma unroll
    for (int kk = 0; kk < 4; ++kk) {
      bf16x8 a[2], b[2];
#pragma unroll
      for (int mr = 0; mr < 2; ++mr) {
        const int grp = (mt & 1) * 4 + wm * 2 + mr;
        a[mr] = *(const bf16x8*)(abase + ks * TILE_B + kk * 8192 +
                                 grp * 1024 + l * 16);
      }
#pragma unroll
      for (int nr = 0; nr < 2; ++nr) {
        const int r = wn * 64 + nr * 32 + lr;
        const int c2 = kk * 32 + lh * 16;
        b[nr] = *(const bf16x8*)(lds + r * 128 + (c2 ^ ((r & 7) << 4)));
      }
#pragma unroll
      for (int mr = 0; mr < 2; ++mr)
#pragma unroll
        for (int nr = 0; nr < 2; ++nr)
          acc[mr][nr] = __builtin_amdgcn_mfma_f32_32x32x16_bf16(
              a[mr], b[nr], acc[mr][nr], 0, 0, 0);
    }
    __syncthreads();
  }

#pragma unroll
  for (int mr = 0; mr < 2; ++mr)
#pragma unroll
    for (int nr = 0; nr < 2; ++nr) {
      const int gc = n0 + wn * 64 + nr * 32 + lr;
      if (gc < NCOLS) {
#pragma unroll
        for (int reg = 0; reg < 16; ++reg) {
          const int row = (reg & 3) + 8 * (reg >> 2) + 4 * lh;
          const int gr = mt * 128 + wm * 64 + mr * 32 + row;
          out[(size_t)gr * NCOLS + gc] = acc[mr][nr][reg];
        }
      }
    }
}

extern "C" void kernel_launch(void* const* d_in, const int* in_sizes, int n_in,
                              void* d_out, int out_size, void* d_ws, size_t ws_size,
                              hipStream_t stream) {
  const int*   ids       = (const int*)d_in[0];
  const float* W_emb     = (const float*)d_in[1];
  const float* W_rev     = (const float*)d_in[2];
  const float* padding   = (const float*)d_in[3];
  const int*   syn_table = (const int*)d_in[4];
  const int*   syn_mask  = (const int*)d_in[5];
  float* out = (float*)d_out;
  char*  ws  = (char*)d_ws;

  const size_t A_BYTES = (size_t)4 * 12 * TILE_B;        // 1.5 MB
  const size_t B_BYTES = (size_t)NT256 * 12 * TILE_B;    // ~146 MB

  hipLaunchKernelGGL(emb_kernel, dim3(NROWS), dim3(256), 0, stream,
                     ids, W_emb, padding, syn_table, syn_mask, ws);

  if (ws_size >= A_BYTES + B_BYTES) {
    char* Bbuf = ws + A_BYTES;
    hipLaunchKernelGGL(conv_kernel, dim3(NT256 * 2, 12), dim3(256), 0, stream,
                       W_rev, Bbuf);
    // 1488 blocks: 4 m-tiles x 372 n-tiles = 8 XCDs x 186 (bijective remap)
    hipLaunchKernelGGL(gemm_reg, dim3(4 * NT256), dim3(512), 0, stream,
                       ws, Bbuf, out);
  } else {
    hipLaunchKernelGGL(gemm_fb, dim3(8, (NCOLS + 127) / 128), dim3(256), 0,
                       stream, W_rev, ws, out);
  }
}

// Round 10
// 346.118 us; speedup vs baseline: 1.2224x; 1.2224x over previous
//
#include <hip/hip_runtime.h>
#include <stdint.h>

#define EFFECT_DIM 758
#define ADD_DIM 10
#define EMBED_DIM 768
#define NCOLS 95000
#define NSYN 8
#define NROWS 1024
#define TILE_B 32768         // bytes per 256x64 bf16 A tile (fragment-ordered)
#define NT64 1485            // ceil(95000/64)
#define NWG (2 * NT64)       // 2970 blocks (mt x nt)

typedef __attribute__((ext_vector_type(8))) __bf16 bf16x8;
typedef __attribute__((ext_vector_type(16))) float f32x16;
typedef __attribute__((ext_vector_type(4))) uint32_t u32x4;

// Fragment order (16-k block): frag(kb16, grp32rows) = 1KB, lane (row&31)+
// (khalf8<<5), 16B/lane = 8 consecutive k as bf16.
// A tile layout (ws): tile(mtq,ks) at (mtq*12+ks)*32768; +kk*8192+grp*1024+lane*16.

// single-instruction f32 pair -> packed bf16 (RNE)
static __device__ __forceinline__ uint32_t pack2(float a, float b) {
  uint32_t r;
  asm("v_cvt_pk_bf16_f32 %0, %1, %2" : "=v"(r) : "v"(a), "v"(b));
  return r;
}

#define F4C(f, i) ((i) == 0 ? (f).x : (i) == 1 ? (f).y : (i) == 2 ? (f).z : (f).w)

// ---------------------------------------------------------------------------
// Kernel 1: VirtualEmbedding -> bf16 A tiles (4 m-tiles x 12 ks), frag order.
// (unchanged from R9 — verified correct)
// ---------------------------------------------------------------------------
__global__ __launch_bounds__(256) void emb_kernel(
    const int* __restrict__ ids, const float* __restrict__ W_emb,
    const float* __restrict__ padding, const int* __restrict__ syn_table,
    const int* __restrict__ syn_mask, char* __restrict__ ws)
{
  const int l = blockIdx.x;
  const int t = threadIdx.x;
  const int id = ids[l];
  int sid[NSYN];
  int msk[NSYN];
#pragma unroll
  for (int k = 0; k < NSYN; ++k) {
    sid[k] = syn_table[id * NSYN + k];
    msk[k] = syn_mask[id * NSYN + k];
  }

  double p[9] = {0, 0, 0, 0, 0, 0, 0, 0, 0};
  for (int d = t; d < EFFECT_DIM; d += 256) {
    p[0] += (double)W_emb[(size_t)id * EFFECT_DIM + d];
#pragma unroll
    for (int k = 0; k < NSYN; ++k)
      p[k + 1] += (double)W_emb[(size_t)sid[k] * EFFECT_DIM + d];
  }

  __shared__ double s_red[9][4];
  const int w = t >> 6;
#pragma unroll
  for (int k = 0; k < 9; ++k) {
    double v = p[k];
#pragma unroll
    for (int off = 32; off > 0; off >>= 1) v += __shfl_down(v, off, 64);
    if ((t & 63) == 0) s_red[k][w] = v;
  }
  __syncthreads();

  const double isum = s_red[0][0] + s_red[0][1] + s_red[0][2] + s_red[0][3];
  float coef[NSYN];
#pragma unroll
  for (int k = 0; k < NSYN; ++k) {
    double ss = s_red[k + 1][0] + s_red[k + 1][1] + s_red[k + 1][2] + s_red[k + 1][3];
    coef[k] = msk[k] ? (float)(isum / ss) : 0.0f;
  }

  const int r = l & 255;               // row within 256-row tile
  char* wbase = ws + (size_t)(l >> 8) * (12 * TILE_B);

  for (int j = t; j < 384; j += 256) { // bf16-pair index over 768 cols
    const int d0 = 2 * j;
    float v0, v1;
    if (d0 < EFFECT_DIM) {
      const float* bp = W_emb + (size_t)id * EFFECT_DIM + d0;
      v0 = bp[0];
      v1 = bp[1];
#pragma unroll
      for (int k = 0; k < NSYN; ++k) {
        const float* sp = W_emb + (size_t)sid[k] * EFFECT_DIM + d0;
        v0 = fmaf(coef[k], sp[0], v0);
        v1 = fmaf(coef[k], sp[1], v1);
      }
    } else {
      v0 = padding[l * ADD_DIM + (d0 - EFFECT_DIM)];
      v1 = padding[l * ADD_DIM + (d0 + 1 - EFFECT_DIM)];
    }
    const int ks   = j >> 5;           // 64-k tile
    const int jl   = j & 31;           // k-pair within tile
    const int kk   = jl >> 3;          // 16-k block
    const int byte = (jl & 7) * 4;     // k-pair byte within 32B half-row
    const int lane = (r & 31) + ((byte >> 4) << 5);
    *(uint32_t*)(wbase + ks * TILE_B + kk * 8192 + (r >> 5) * 1024 +
                 lane * 16 + (byte & 15)) = pack2(v0, v1);
  }
}

// ---------------------------------------------------------------------------
// Kernel 2: B-K-resident fused GEMM. Tile M=512 x N=64, K=768 entire.
// Prologue: stage full B panel (64n x 768k) f32->bf16 into frag-ordered LDS
// (96KB) ONCE — conv pass eliminated. One barrier. Then a BARRIER-FREE
// K-loop: per 16-k block each wave loads 2 A frags (coalesced 1KB dwordx4,
// L2-hot) + 2 LDS b128 (conflict-free) + 4 MFMA. 8 waves (one per 64-row
// slice), acc 2x2. Bijective XCD remap co-locates the 2 mt-siblings of each
// B panel for L2 reuse.
// ---------------------------------------------------------------------------
__global__ __launch_bounds__(512, 2) void gemm_kres(
    const float* __restrict__ Wrev, const char* __restrict__ Abuf,
    float* __restrict__ out)
{
  __shared__ char lds[98304];  // B frags: kb*2048 + ng*1024 + lane*16
  const int t = threadIdx.x;
  const int l = t & 63;
  const int w = t >> 6;        // 0..7

  // bijective XCD remap (m204): nwg=2970, q=371, r=2
  const int orig = blockIdx.x;
  const int xcd  = orig & 7;
  const int q = NWG / 8, rr = NWG % 8;
  const int chunk0 = (xcd < rr) ? xcd * (q + 1) : rr * (q + 1) + (xcd - rr) * q;
  const int work = chunk0 + (orig >> 3);
  const int mt = work & 1;
  const int nt = work >> 1;
  const int n0 = nt * 64;

  // ---- prologue: stage B panel f32 -> bf16 frag LDS (3 rounds x 256 k) ----
  {
    const int kc = t >> 4;          // 0..31: 8-k row group
    const int n4 = (t & 15) * 4;    // n quad within 64
    const bool valid = (n0 + n4 + 4) <= NCOLS;   // NCOLS % 4 == 0
#pragma unroll
    for (int rnd = 0; rnd < 3; ++rnd) {
      const int kbase = rnd * 256 + kc * 8;
      float4 v[8];
      const float* p = Wrev + (size_t)kbase * NCOLS + n0 + n4;
#pragma unroll
      for (int j = 0; j < 8; ++j)
        v[j] = valid ? *(const float4*)(p + (size_t)j * NCOLS)
                     : float4{0.0f, 0.0f, 0.0f, 0.0f};
      const int kb = kbase >> 4;
      const int kh = kc & 1;
#pragma unroll
      for (int i = 0; i < 4; ++i) {
        const int n = n4 + i;
        u32x4 u;
#pragma unroll
        for (int j2 = 0; j2 < 4; ++j2)
          u[j2] = pack2(F4C(v[2 * j2], i), F4C(v[2 * j2 + 1], i));
        *(u32x4*)(lds + kb * 2048 + (n >> 5) * 1024 +
                  ((n & 31) + (kh << 5)) * 16) = u;
      }
    }
  }
  __syncthreads();

  // ---- barrier-free K-loop ----
  // wave w owns m-groups {g0, g0+1}, g0 = mt*16 + 2w; both in A tile
  // mtq0 = mt*2 + (w>>2) at grp0 = 2*(w&3).
  const int mtq0 = mt * 2 + (w >> 2);
  const int grp0 = (w & 3) * 2;
  const char* abase = Abuf + (size_t)mtq0 * (12 * TILE_B) + grp0 * 1024 + l * 16;

  f32x16 acc[2][2] = {};

  for (int ks = 0; ks < 12; ++ks) {
    const char* at = abase + ks * TILE_B;
    const char* bt = lds + ks * 8192 + l * 16;   // 4 kb of 2048B each
#pragma unroll
    for (int kk = 0; kk < 4; ++kk) {
      bf16x8 a0 = *(const bf16x8*)(at + kk * 8192);
      bf16x8 a1 = *(const bf16x8*)(at + kk * 8192 + 1024);
      bf16x8 b0 = *(const bf16x8*)(bt + kk * 2048);
      bf16x8 b1 = *(const bf16x8*)(bt + kk * 2048 + 1024);
      acc[0][0] = __builtin_amdgcn_mfma_f32_32x32x16_bf16(a0, b0, acc[0][0], 0, 0, 0);
      acc[0][1] = __builtin_amdgcn_mfma_f32_32x32x16_bf16(a0, b1, acc[0][1], 0, 0, 0);
      acc[1][0] = __builtin_amdgcn_mfma_f32_32x32x16_bf16(a1, b0, acc[1][0], 0, 0, 0);
      acc[1][1] = __builtin_amdgcn_mfma_f32_32x32x16_bf16(a1, b1, acc[1][1], 0, 0, 0);
    }
  }

  // ---- epilogue: C layout col=lane&31, row=(reg&3)+8*(reg>>2)+4*(lane>>5) ----
  const int rbase = (mtq0 * 8 + grp0) * 32 + 4 * (l >> 5);
#pragma unroll
  for (int nr = 0; nr < 2; ++nr) {
    const int gc = n0 + nr * 32 + (l & 31);
    if (gc < NCOLS) {
#pragma unroll
      for (int mr = 0; mr < 2; ++mr)
#pragma unroll
        for (int reg = 0; reg < 16; ++reg) {
          const int row = rbase + mr * 32 + (reg & 3) + 8 * (reg >> 2);
          out[(size_t)row * NCOLS + gc] = acc[mr][nr][reg];
        }
    }
  }
}

extern "C" void kernel_launch(void* const* d_in, const int* in_sizes, int n_in,
                              void* d_out, int out_size, void* d_ws, size_t ws_size,
                              hipStream_t stream) {
  const int*   ids       = (const int*)d_in[0];
  const float* W_emb     = (const float*)d_in[1];
  const float* W_rev     = (const float*)d_in[2];
  const float* padding   = (const float*)d_in[3];
  const int*   syn_table = (const int*)d_in[4];
  const int*   syn_mask  = (const int*)d_in[5];
  float* out = (float*)d_out;
  char*  ws  = (char*)d_ws;

  // A tiles occupy ws[0, 1.5MB)
  hipLaunchKernelGGL(emb_kernel, dim3(NROWS), dim3(256), 0, stream,
                     ids, W_emb, padding, syn_table, syn_mask, ws);

  hipLaunchKernelGGL(gemm_kres, dim3(NWG), dim3(512), 0, stream,
                     W_rev, ws, out);
}